// Round 3
// baseline (174.821 us; speedup 1.0000x reference)
//
#include <hip/hip_runtime.h>

// EvolutionModelTorch — Jukes-Cantor pair-likelihood.
// Analytic JC: T(t) = 1/4 + 3/4 e^{-4t/3} on diag, 1/4 - 1/4 e^{-4t/3} off-diag.
// y[c] = e * x[c] + 0.25*(1-e)*S,  S = sum_v x[v].
// joint[b,m,c] = y1[c] * y2[c] * p,  p = exp((log10 - 10(t1+t2))/8192)  (p folded into y1)
// log_p[b] = sum_m log(0.25 * sum_c joint[b,m,c])
//
// R1 lesson: VGPR=28 meant loads were serialized (2 VMEM in flight/wave) ->
// latency-bound at 2.1 TB/s. This version stages all 8 loads up front.
// R2 lesson: __builtin_nontemporal_store needs a clang ext_vector type, not
// HIP's float4 class.

typedef float vfloat4 __attribute__((ext_vector_type(4)));

constexpr int SEQ_LEN = 8192;
constexpr int BATCH   = 512;
constexpr int TPB     = 256;
constexpr int CHUNKS  = 8;                        // blocks per batch
constexpr int SPT     = SEQ_LEN / (CHUNKS * TPB); // float4-sites per thread = 4

__global__ __launch_bounds__(TPB) void evo_main(
    const float* __restrict__ f1, const float* __restrict__ br1,
    const float* __restrict__ f2, const float* __restrict__ br2,
    float* __restrict__ joint, float* __restrict__ logp)
{
    const int blk   = blockIdx.x;
    const int b     = blk >> 3;              // / CHUNKS
    const int chunk = blk & (CHUNKS - 1);

    const float t1 = br1[b];
    const float t2 = br2[b];
    const float e1 = __expf(-(4.0f / 3.0f) * t1);
    const float e2 = __expf(-(4.0f / 3.0f) * t2);
    const float p  = __expf((2.3025850929940457f - 10.0f * (t1 + t2)) * (1.0f / (float)SEQ_LEN));
    const float pe1 = p * e1;                      // prior folded into feature-1 affine map
    const float pc1 = p * 0.25f * (1.0f - e1);
    const float c2  = 0.25f * (1.0f - e2);

    const size_t base = (size_t)b * SEQ_LEN + (size_t)chunk * (TPB * SPT);
    const vfloat4* __restrict__ F1 = (const vfloat4*)f1 + base;
    const vfloat4* __restrict__ F2 = (const vfloat4*)f2 + base;
    vfloat4* __restrict__ J = (vfloat4*)joint + base;

    // Stage ALL loads first: 8 global_load_dwordx4 in flight per wave before
    // any waitcnt (compile-time indices -> registers, rule #20 safe).
    vfloat4 x[SPT], y[SPT];
#pragma unroll
    for (int k = 0; k < SPT; ++k) x[k] = F1[k * TPB + (int)threadIdx.x];
#pragma unroll
    for (int k = 0; k < SPT; ++k) y[k] = F2[k * TPB + (int)threadIdx.x];

    float lsum = 0.0f;
#pragma unroll
    for (int k = 0; k < SPT; ++k) {
        const float a1 = pc1 * ((x[k].x + x[k].y) + (x[k].z + x[k].w));
        const float a2 = c2  * ((y[k].x + y[k].y) + (y[k].z + y[k].w));
        vfloat4 o;
        o.x = fmaf(pe1, x[k].x, a1) * fmaf(e2, y[k].x, a2);
        o.y = fmaf(pe1, x[k].y, a1) * fmaf(e2, y[k].y, a2);
        o.z = fmaf(pe1, x[k].z, a1) * fmaf(e2, y[k].z, a2);
        o.w = fmaf(pe1, x[k].w, a1) * fmaf(e2, y[k].w, a2);
        // joint is write-once, never re-read in-kernel: nontemporal keeps L3 for inputs
        __builtin_nontemporal_store(o, &J[k * TPB + (int)threadIdx.x]);
        lsum += __logf(0.25f * ((o.x + o.y) + (o.z + o.w)));
    }

    // wave64 down-reduce
#pragma unroll
    for (int off = 32; off > 0; off >>= 1)
        lsum += __shfl_down(lsum, off, 64);

    __shared__ float wsum[TPB / 64];
    const int lane = threadIdx.x & 63;
    const int wid  = threadIdx.x >> 6;
    if (lane == 0) wsum[wid] = lsum;
    __syncthreads();
    if (threadIdx.x == 0) {
        const float s = (wsum[0] + wsum[1]) + (wsum[2] + wsum[3]);
        atomicAdd(&logp[b], s);   // 8 atomics per batch
    }
}

extern "C" void kernel_launch(void* const* d_in, const int* in_sizes, int n_in,
                              void* d_out, int out_size, void* d_ws, size_t ws_size,
                              hipStream_t stream) {
    const float* f1  = (const float*)d_in[0];
    const float* br1 = (const float*)d_in[1];
    const float* f2  = (const float*)d_in[2];
    const float* br2 = (const float*)d_in[3];
    float* joint = (float*)d_out;
    float* logp  = joint + (size_t)BATCH * SEQ_LEN * 4;

    // log_p region is poisoned 0xAA before every timed call -> zero it (graph-legal)
    (void)hipMemsetAsync(logp, 0, BATCH * sizeof(float), stream);

    evo_main<<<BATCH * CHUNKS, TPB, 0, stream>>>(f1, br1, f2, br2, joint, logp);
}

// Round 4
// 173.855 us; speedup vs baseline: 1.0056x; 1.0056x over previous
//
#include <hip/hip_runtime.h>

// EvolutionModelTorch — Jukes-Cantor pair-likelihood.
// Analytic JC: T(t) = 1/4 + 3/4 e^{-4t/3} on diag, 1/4 - 1/4 e^{-4t/3} off-diag.
// y[c] = e * x[c] + 0.25*(1-e)*S,  S = sum_v x[v].
// joint[b,m,c] = y1[c] * y2[c] * p,  p = exp((log10 - 10(t1+t2))/8192)
// log_p[b] = sum_m log(0.25 * sum_c joint[b,m,c])
//
// R1/R3 lesson: compiler sinks staged loads back into the loop (VGPR stayed 28,
// ~2 VMEM in flight, 2.28 TB/s latency-bound). Fix: sched_barrier(0) pins the
// 8-load cluster before any compute/waitcnt.

typedef float vfloat4 __attribute__((ext_vector_type(4)));

constexpr int SEQ_LEN = 8192;
constexpr int BATCH   = 512;
constexpr int TPB     = 256;
constexpr int CHUNKS  = 8;                        // blocks per batch
constexpr int SPT     = SEQ_LEN / (CHUNKS * TPB); // float4-sites per thread = 4

__global__ __launch_bounds__(TPB) void evo_main(
    const float* __restrict__ f1, const float* __restrict__ br1,
    const float* __restrict__ f2, const float* __restrict__ br2,
    float* __restrict__ joint, float* __restrict__ logp)
{
    const int blk   = blockIdx.x;
    const int b     = blk >> 3;              // / CHUNKS
    const int chunk = blk & (CHUNKS - 1);
    const int tid   = (int)threadIdx.x;

    const float t1 = br1[b];
    const float t2 = br2[b];
    const float e1 = __expf(-(4.0f / 3.0f) * t1);
    const float e2 = __expf(-(4.0f / 3.0f) * t2);
    const float p  = __expf((2.3025850929940457f - 10.0f * (t1 + t2)) * (1.0f / (float)SEQ_LEN));
    const float pe1 = p * e1;                      // prior folded into feature-1 affine map
    const float pc1 = p * 0.25f * (1.0f - e1);
    const float c2  = 0.25f * (1.0f - e2);

    const size_t base = (size_t)b * SEQ_LEN + (size_t)chunk * (TPB * SPT);
    const vfloat4* __restrict__ F1 = (const vfloat4*)f1 + base;
    const vfloat4* __restrict__ F2 = (const vfloat4*)f2 + base;
    vfloat4* __restrict__ J = (vfloat4*)joint + base;

    // Issue ALL 8 loads (interleaved x/y pairs so the oldest-first vmcnt peel
    // matches consumption order), then pin them with a full sched_barrier so
    // the scheduler cannot sink them back into the compute loop.
    vfloat4 x[SPT], y[SPT];
#pragma unroll
    for (int k = 0; k < SPT; ++k) {
        x[k] = F1[k * TPB + tid];
        y[k] = F2[k * TPB + tid];
    }
    __builtin_amdgcn_sched_barrier(0);

    float lsum = 0.0f;
#pragma unroll
    for (int k = 0; k < SPT; ++k) {
        const float a1 = pc1 * ((x[k].x + x[k].y) + (x[k].z + x[k].w));
        const float a2 = c2  * ((y[k].x + y[k].y) + (y[k].z + y[k].w));
        vfloat4 o;
        o.x = fmaf(pe1, x[k].x, a1) * fmaf(e2, y[k].x, a2);
        o.y = fmaf(pe1, x[k].y, a1) * fmaf(e2, y[k].y, a2);
        o.z = fmaf(pe1, x[k].z, a1) * fmaf(e2, y[k].z, a2);
        o.w = fmaf(pe1, x[k].w, a1) * fmaf(e2, y[k].w, a2);
        // joint is write-once, never re-read in-kernel
        __builtin_nontemporal_store(o, &J[k * TPB + tid]);
        lsum += __logf(0.25f * ((o.x + o.y) + (o.z + o.w)));
    }

    // wave64 down-reduce
#pragma unroll
    for (int off = 32; off > 0; off >>= 1)
        lsum += __shfl_down(lsum, off, 64);

    __shared__ float wsum[TPB / 64];
    const int lane = threadIdx.x & 63;
    const int wid  = threadIdx.x >> 6;
    if (lane == 0) wsum[wid] = lsum;
    __syncthreads();
    if (threadIdx.x == 0) {
        const float s = (wsum[0] + wsum[1]) + (wsum[2] + wsum[3]);
        atomicAdd(&logp[b], s);   // 8 atomics per batch
    }
}

extern "C" void kernel_launch(void* const* d_in, const int* in_sizes, int n_in,
                              void* d_out, int out_size, void* d_ws, size_t ws_size,
                              hipStream_t stream) {
    const float* f1  = (const float*)d_in[0];
    const float* br1 = (const float*)d_in[1];
    const float* f2  = (const float*)d_in[2];
    const float* br2 = (const float*)d_in[3];
    float* joint = (float*)d_out;
    float* logp  = joint + (size_t)BATCH * SEQ_LEN * 4;

    // log_p region is poisoned 0xAA before every timed call -> zero it (graph-legal)
    (void)hipMemsetAsync(logp, 0, BATCH * sizeof(float), stream);

    evo_main<<<BATCH * CHUNKS, TPB, 0, stream>>>(f1, br1, f2, br2, joint, logp);
}